// Round 5
// baseline (1703.731 us; speedup 1.0000x reference)
//
#include <hip/hip_runtime.h>
#include <hip/hip_bf16.h>
#include <stdint.h>

#define T_STEPS 512
#define BATCH   256
#define DIN     85
#define HDIM    512
#define NOUT    33

#define BBLK  16     // batch rows per group
#define HS    32     // H columns per block
#define LDA   1040   // bytes per padded row of h A-tile (520 elems, 16B-aligned)
#define LDX   208    // bytes per padded row of x A-tile (104 elems)

// bf16 NaN|NaN pair — unreachable as packed h output (|h|<1, finite),
// used as the "not yet written" sentinel so the data is its own flag.
#define SENT  0x7FC07FC0u

typedef __attribute__((ext_vector_type(8))) short s8v;       // 8 x bf16
typedef __attribute__((ext_vector_type(4))) float f4v;       // MFMA accumulator
typedef __attribute__((ext_vector_type(4))) uint32_t u32x4;  // 16B chunk

__device__ __forceinline__ uint16_t f2bf(float f) {
    uint32_t x = __builtin_bit_cast(uint32_t, f);
    uint32_t r = (x + 0x7fffu + ((x >> 16) & 1u)) >> 16;
    return (uint16_t)r;
}
__device__ __forceinline__ float sigm(float v) {
    v = fminf(fmaxf(v, -30.f), 30.f);
    return 1.f / (1.f + __expf(-v));
}
__device__ __forceinline__ float tanh_f(float v) {
    v = fminf(fmaxf(v, -15.f), 15.f);
    float e = __expf(2.f * v);
    return (e - 1.f) / (e + 1.f);
}
__device__ __forceinline__ s8v cvt8(const float* p) {
    s8v v;
#pragma unroll
    for (int j = 0; j < 8; ++j) v[j] = (short)f2bf(p[j]);
    return v;
}

// r11: agent-scope (MALL) exchange only — the r4/r8-proven protocol. The
// sc0-only "XCD-L2 coherence" path (r10) was falsified on HW: consumers read
// stale sentinels, which the activation clamps launder into finite wrong
// values (v_max_f32(NaN,x)=x). Reverted.
__device__ __forceinline__ void issue4_dev(u32x4& v, const uint32_t* p) {
    asm volatile("global_load_dwordx4 %0, %1, off sc0 sc1"
                 : "+v"(v) : "v"(p) : "memory");
}
__device__ __forceinline__ void wait_vm0(u32x4& a, u32x4& b, u32x4& c, u32x4& d) {
    // "+v" ties make the sentinel checks data-dependent on this wait — the
    // compiler cannot hoist them past it (rule 18).
    asm volatile("s_waitcnt vmcnt(0)"
                 : "+v"(a), "+v"(b), "+v"(c), "+v"(d) :: "memory");
}
__device__ __forceinline__ uint32_t has_sent(const u32x4& v) {
    return (uint32_t)(v[0] == SENT) | (uint32_t)(v[1] == SENT) |
           (uint32_t)(v[2] == SENT) | (uint32_t)(v[3] == SENT);
}

// Fill hbuf with the sentinel before the recurrence.
__global__ __launch_bounds__(256) void lstm_init(uint32_t* __restrict__ hbuf)
{
    const size_t n4 = (size_t)(T_STEPS + 1) * BATCH * HDIM / 2 / 4;
    u32x4 s; s[0] = SENT; s[1] = SENT; s[2] = SENT; s[3] = SENT;
    u32x4* p = (u32x4*)hbuf;
    for (size_t i = (size_t)blockIdx.x * 256 + threadIdx.x; i < n4;
         i += (size_t)gridDim.x * 256)
        p[i] = s;
}

// Persistent recurrence kernel. 256 blocks = 16 groups x 16 members.
// Group owns 16 batch rows; member owns 32 H columns (x4 gates, one per wave).
// Weights live in registers as MFMA B-fragments for the whole kernel.
// r11 changes vs r8 (all agent-scope-safe):
//  - LATE poll issue: polls go out AFTER the h-store, so round 1 samples the
//    MALL after symmetric peers' stores land (r8's early issue guaranteed an
//    all-sentinel first round: ~1 extra RTT + 4MB extra MALL traffic/step).
//  - own 32 columns written straight into hA LDS by the pointwise threads;
//    the 16 threads whose poll chunks are the own columns skip polling.
//  - bias+activation hoisted pre-barrier onto the 4 producer waves; the
//    post-barrier pointwise is 2 FMA + tanh + pack -> h-store issues earlier.
__global__ __launch_bounds__(256, 1) void lstm_rec(
    const float* __restrict__ x,
    const float* __restrict__ Wxi, const float* __restrict__ Wxf,
    const float* __restrict__ Wxo, const float* __restrict__ Wxc,
    const float* __restrict__ Whi, const float* __restrict__ bhi,
    const float* __restrict__ Whf, const float* __restrict__ bhf,
    const float* __restrict__ Who, const float* __restrict__ bho,
    const float* __restrict__ Whc, const float* __restrict__ bhc,
    uint16_t* __restrict__ hbuf)      // [T_STEPS+1][BATCH][HDIM] bf16 (scratch)
{
    __shared__ __align__(16) uint8_t hA[16 * LDA];   // 16.6 KB
    __shared__ __align__(16) uint8_t xA[16 * LDX];   // 3.3 KB
    __shared__ float gbuf[4 * 16 * 33];              // 8.4 KB

    const int tid  = threadIdx.x;
    const int bid  = blockIdx.x;
    const int xcd  = bid & 7;
    const int slot = bid >> 3;
    const int grp  = xcd * 2 + (slot >> 4);
    const int mem  = slot & 15;
    const int b0   = grp * BBLK;
    const int hs   = mem * HS;

    const int wave  = tid >> 6;       // gate: 0=i 1=f 2=o 3=c
    const int lane  = tid & 63;
    const int col16 = lane & 15;
    const int quad  = lane >> 4;

    const float* Wh  = (wave == 0) ? Whi : (wave == 1) ? Whf : (wave == 2) ? Who : Whc;
    const float* Wxp = (wave == 0) ? Wxi : (wave == 1) ? Wxf : (wave == 2) ? Wxo : Wxc;
    const float* bg  = (wave == 0) ? bhi : (wave == 1) ? bhf : (wave == 2) ? bho : bhc;

    // ---- B-fragments (weights) into registers, once (fp32 -> bf16 RNE) ----
    s8v bh[2][16];
#pragma unroll
    for (int nt = 0; nt < 2; ++nt) {
        const float* rowp = Wh + (size_t)(hs + nt * 16 + col16) * HDIM;
#pragma unroll
        for (int kt = 0; kt < 16; ++kt)
            bh[nt][kt] = cvt8(rowp + kt * 32 + quad * 8);
    }
    s8v bx[2][3];
#pragma unroll
    for (int nt = 0; nt < 2; ++nt) {
        const float* rowp = Wxp + (size_t)(hs + nt * 16 + col16) * DIN;
#pragma unroll
        for (int kt = 0; kt < 3; ++kt) {
            s8v v;
#pragma unroll
            for (int j = 0; j < 8; ++j) {
                int k = kt * 32 + quad * 8 + j;
                v[j] = (k < DIN) ? (short)f2bf(rowp[k]) : (short)0;
            }
            bx[nt][kt] = v;
        }
    }
    // per-wave gate bias for the producer-side activation
    const float bg0 = bg[hs + col16];
    const float bg1 = bg[hs + 16 + col16];

    // ---- pointwise mapping: thread -> (row r, cols c0,c0+1) of 16x32 slice ----
    const int r  = tid >> 4;
    const int c0 = (tid & 15) * 2;
    float C0 = 0.f, C1 = 0.f;

    uint32_t* hbuf32 = (uint32_t*)hbuf;
    const size_t hslot = ((size_t)(b0 + r) * HDIM + hs + c0) >> 1;

    // ---- refill chunk mapping: chunk c = tid + 256q -> row c>>6, 16B col c&63
    const int rrow[4] = { tid >> 6, (tid + 256) >> 6, (tid + 512) >> 6, (tid + 768) >> 6 };
    const int rc8     = tid & 63;
    // own 32 columns = 4 chunk-cols; they arrive via LDS, never via poll
    const uint32_t ownm = (rc8 >= mem * 4 && rc8 < mem * 4 + 4) ? 1u : 0u;

    // ---- x prefetch (fp32 registers) ----
    float xreg[6];
    auto load_x = [&](int t) {
#pragma unroll
        for (int j = 0; j < 6; ++j) {
            int v = tid + j * 256;
            int row = v / 96, k = v % 96;
            xreg[j] = (k < DIN) ? x[(size_t)(t * BATCH + b0 + row) * DIN + k] : 0.f;
        }
    };
    auto store_x = [&]() {
#pragma unroll
        for (int j = 0; j < 6; ++j) {
            int v = tid + j * 256;
            int row = v / 96, k = v % 96;
            *(uint16_t*)(xA + row * LDX + k * 2) = f2bf(xreg[j]);
        }
    };

    // init: h(0)=0 in LDS, stage x(0)
    load_x(0);
    for (int j = tid; j < 16 * LDA / 16; j += 256) {
        s8v z;
#pragma unroll
        for (int q = 0; q < 8; ++q) z[q] = 0;
        ((s8v*)hA)[j] = z;
    }
    store_x();
    __syncthreads();

    u32x4 v0 = {SENT, SENT, SENT, SENT};
    u32x4 v1 = v0, v2 = v0, v3 = v0;

    for (int t = 0; t < T_STEPS; ++t) {
        const int last = (t == T_STEPS - 1);

        // x(t+1) loads fly under the GEMM (arrived by store_x time)
        if (!last) load_x(t + 1);

        // ---- GEMM: pre-activations for this wave's gate, 16 rows x 32 cols ----
        f4v acc0 = {0.f, 0.f, 0.f, 0.f}, acc1 = {0.f, 0.f, 0.f, 0.f};
#pragma unroll
        for (int kt = 0; kt < 16; ++kt) {
            s8v a = *(const s8v*)(hA + col16 * LDA + kt * 64 + quad * 16);
            acc0 = __builtin_amdgcn_mfma_f32_16x16x32_bf16(a, bh[0][kt], acc0, 0, 0, 0);
            acc1 = __builtin_amdgcn_mfma_f32_16x16x32_bf16(a, bh[1][kt], acc1, 0, 0, 0);
        }
#pragma unroll
        for (int kt = 0; kt < 3; ++kt) {
            s8v a = *(const s8v*)(xA + col16 * LDX + kt * 64 + quad * 16);
            acc0 = __builtin_amdgcn_mfma_f32_16x16x32_bf16(a, bx[0][kt], acc0, 0, 0, 0);
            acc1 = __builtin_amdgcn_mfma_f32_16x16x32_bf16(a, bx[1][kt], acc1, 0, 0, 0);
        }
        // bias + activation on the producer wave (parallel across 4 waves,
        // off the post-barrier serial path). C/D layout: col=lane&15, row=quad*4+rr.
        // Identical math/order to the consumer-side version -> bit-identical.
#pragma unroll
        for (int rr = 0; rr < 4; ++rr) {
            float a0 = acc0[rr] + bg0;
            float a1 = acc1[rr] + bg1;
            if (wave == 3) { a0 = tanh_f(a0); a1 = tanh_f(a1); }
            else           { a0 = sigm(a0);   a1 = sigm(a1);   }
            int b = quad * 4 + rr;
            gbuf[(wave * 16 + b) * 33 + col16]      = a0;
            gbuf[(wave * 16 + b) * 33 + 16 + col16] = a1;
        }

        __syncthreads();

        if (!last) store_x();   // xA free after barrier; x regs arrived in GEMM

        // ---- pointwise (gates pre-activated): 2 FMA + tanh(C) + pack ----
        float I0 = gbuf[(0 * 16 + r) * 33 + c0], I1 = gbuf[(0 * 16 + r) * 33 + c0 + 1];
        float F0 = gbuf[(1 * 16 + r) * 33 + c0], F1 = gbuf[(1 * 16 + r) * 33 + c0 + 1];
        float O0 = gbuf[(2 * 16 + r) * 33 + c0], O1 = gbuf[(2 * 16 + r) * 33 + c0 + 1];
        float G0 = gbuf[(3 * 16 + r) * 33 + c0], G1 = gbuf[(3 * 16 + r) * 33 + c0 + 1];
        C0 = F0 * C0 + I0 * G0;
        C1 = F1 * C1 + I1 * G1;
        float h0 = O0 * tanh_f(C0);
        float h1 = O1 * tanh_f(C1);

        // fire-and-forget agent store (coherence point); no fence, no drain
        uint32_t packed = (uint32_t)f2bf(h0) | ((uint32_t)f2bf(h1) << 16);
        __hip_atomic_store(&hbuf32[(size_t)(t + 1) * (BATCH * HDIM / 2) + hslot],
                           packed, __ATOMIC_RELAXED, __HIP_MEMORY_SCOPE_AGENT);

        if (last) break;

        // own columns go straight to LDS — no exchange round-trip for them
        *(uint32_t*)(hA + r * LDA + (hs + c0) * 2) = packed;

        // ---- LATE poll issue: round 1 samples MALL after peers' stores ----
        const uint32_t* src = hbuf32 + (size_t)(t + 1) * (BATCH * HDIM / 2)
                                     + (size_t)b0 * (HDIM / 2);
        const uint32_t* p0 = src + (size_t)rrow[0] * (HDIM / 2) + rc8 * 4;
        const uint32_t* p1 = src + (size_t)rrow[1] * (HDIM / 2) + rc8 * 4;
        const uint32_t* p2 = src + (size_t)rrow[2] * (HDIM / 2) + rc8 * 4;
        const uint32_t* p3 = src + (size_t)rrow[3] * (HDIM / 2) + rc8 * 4;

        if (!ownm) {
            issue4_dev(v0, p0); issue4_dev(v1, p1);
            issue4_dev(v2, p2); issue4_dev(v3, p3);
        }
        wait_vm0(v0, v1, v2, v3);
        uint32_t s0 = ownm ? 0u : has_sent(v0);
        uint32_t s1 = ownm ? 0u : has_sent(v1);
        uint32_t s2 = ownm ? 0u : has_sent(v2);
        uint32_t s3 = ownm ? 0u : has_sent(v3);
        int round = 0;
        while (s0 | s1 | s2 | s3) {
            if (++round > 50000) break;   // never hang
            if (round >= 8) __builtin_amdgcn_s_sleep(1);
            if (s0) issue4_dev(v0, p0);
            if (s1) issue4_dev(v1, p1);
            if (s2) issue4_dev(v2, p2);
            if (s3) issue4_dev(v3, p3);
            wait_vm0(v0, v1, v2, v3);
            s0 = has_sent(v0); s1 = has_sent(v1);
            s2 = has_sent(v2); s3 = has_sent(v3);
        }
        if (!ownm) {
            *(u32x4*)(hA + rrow[0] * LDA + rc8 * 16) = v0;
            *(u32x4*)(hA + rrow[1] * LDA + rc8 * 16) = v1;
            *(u32x4*)(hA + rrow[2] * LDA + rc8 * 16) = v2;
            *(u32x4*)(hA + rrow[3] * LDA + rc8 * 16) = v3;
        }

        __syncthreads();
    }
}

// Readout: out[t,b,:] = h[t+1] @ Wro^T + bro.  MFMA, N padded 33->48. fp32 out.
__global__ __launch_bounds__(256, 1) void lstm_out(
    const uint16_t* __restrict__ hbuf,
    const float* __restrict__ Wro, const float* __restrict__ bro,
    float* __restrict__ out)
{
    __shared__ __align__(16) uint8_t hT[64 * LDA];   // 66.6 KB

    const int tid   = threadIdx.x;
    const int bid   = blockIdx.x;
    const int wave  = tid >> 6;
    const int lane  = tid & 63;
    const int col16 = lane & 15;
    const int quad  = lane >> 4;

    s8v bw[3][16];
    float bias[3];
#pragma unroll
    for (int nt = 0; nt < 3; ++nt) {
        int o = nt * 16 + col16;
        bias[nt] = (o < NOUT) ? bro[o] : 0.f;
#pragma unroll
        for (int kt = 0; kt < 16; ++kt) {
            if (o < NOUT) {
                bw[nt][kt] = cvt8(Wro + (size_t)o * HDIM + kt * 32 + quad * 8);
            } else {
                s8v z;
#pragma unroll
                for (int q = 0; q < 8; ++q) z[q] = 0;
                bw[nt][kt] = z;
            }
        }
    }

    const uint16_t* hsrc = hbuf + (size_t)BATCH * HDIM;  // skip t=0 slot

    for (int sub = 0; sub < 8; ++sub) {
        size_t row0 = (size_t)bid * 512 + (size_t)sub * 64;
#pragma unroll
        for (int j = 0; j < 16; ++j) {
            int v = tid + j * 256;
            int row = v >> 6, c8 = v & 63;
            s8v val = *(const s8v*)(hsrc + (row0 + row) * HDIM + c8 * 8);
            *(s8v*)(hT + row * LDA + c8 * 16) = val;
        }
        __syncthreads();

        f4v acc[3];
#pragma unroll
        for (int nt = 0; nt < 3; ++nt) acc[nt] = (f4v){0.f, 0.f, 0.f, 0.f};
#pragma unroll
        for (int kt = 0; kt < 16; ++kt) {
            s8v a = *(const s8v*)(hT + (wave * 16 + col16) * LDA + kt * 64 + quad * 16);
#pragma unroll
            for (int nt = 0; nt < 3; ++nt)
                acc[nt] = __builtin_amdgcn_mfma_f32_16x16x32_bf16(a, bw[nt][kt], acc[nt], 0, 0, 0);
        }
#pragma unroll
        for (int nt = 0; nt < 3; ++nt) {
            int o = nt * 16 + col16;
            if (o < NOUT) {
#pragma unroll
                for (int rr = 0; rr < 4; ++rr) {
                    size_t rg = row0 + (size_t)wave * 16 + quad * 4 + rr;
                    out[rg * NOUT + o] = acc[nt][rr] + bias[nt];
                }
            }
        }
        __syncthreads();
    }
}

extern "C" void kernel_launch(void* const* d_in, const int* in_sizes, int n_in,
                              void* d_out, int out_size, void* d_ws, size_t ws_size,
                              hipStream_t stream)
{
    const float* x   = (const float*)d_in[0];
    const float* Wxi = (const float*)d_in[1];
    const float* Wxf = (const float*)d_in[2];
    const float* Wxo = (const float*)d_in[3];
    const float* Wxc = (const float*)d_in[4];
    const float* Whi = (const float*)d_in[5];
    const float* bhi = (const float*)d_in[6];
    const float* Whf = (const float*)d_in[7];
    const float* bhf = (const float*)d_in[8];
    const float* Who = (const float*)d_in[9];
    const float* bho = (const float*)d_in[10];
    const float* Whc = (const float*)d_in[11];
    const float* bhc = (const float*)d_in[12];
    const float* Wro = (const float*)d_in[13];
    const float* bro = (const float*)d_in[14];
    float* out = (float*)d_out;

    uint16_t* hbuf = (uint16_t*)d_ws;   // (T+1)*B*H*2 = 134.5 MB

    lstm_init<<<2048, 256, 0, stream>>>((uint32_t*)hbuf);
    lstm_rec<<<256, 256, 0, stream>>>(x, Wxi, Wxf, Wxo, Wxc,
                                      Whi, bhi, Whf, bhf, Who, bho, Whc, bhc,
                                      hbuf);
    lstm_out<<<256, 256, 0, stream>>>(hbuf, Wro, bro, out);
}

// Round 6
// 1471.733 us; speedup vs baseline: 1.1576x; 1.1576x over previous
//
#include <hip/hip_runtime.h>
#include <hip/hip_bf16.h>
#include <stdint.h>

#define T_STEPS 512
#define BATCH   256
#define DIN     85
#define HDIM    512
#define NOUT    33

#define BBLK  16     // batch rows per group
#define HS    32     // H columns per block
#define LDA   1040   // bytes per padded row of h A-tile (520 elems, 16B-aligned)
#define LDX   208    // bytes per padded row of x A-tile (104 elems)

// bf16 NaN|NaN pair — unreachable as packed h output (|h|<1, finite),
// used as the "not yet written" sentinel so the data is its own flag.
#define SENT  0x7FC07FC0u

typedef __attribute__((ext_vector_type(8))) short s8v;       // 8 x bf16
typedef __attribute__((ext_vector_type(4))) float f4v;       // MFMA accumulator
typedef __attribute__((ext_vector_type(4))) uint32_t u32x4;  // 16B chunk

__device__ __forceinline__ uint16_t f2bf(float f) {
    uint32_t x = __builtin_bit_cast(uint32_t, f);
    uint32_t r = (x + 0x7fffu + ((x >> 16) & 1u)) >> 16;
    return (uint16_t)r;
}
__device__ __forceinline__ float sigm(float v) {
    v = fminf(fmaxf(v, -30.f), 30.f);
    return 1.f / (1.f + __expf(-v));
}
__device__ __forceinline__ float tanh_f(float v) {
    v = fminf(fmaxf(v, -15.f), 15.f);
    float e = __expf(2.f * v);
    return (e - 1.f) / (e + 1.f);
}
__device__ __forceinline__ s8v cvt8(const float* p) {
    s8v v;
#pragma unroll
    for (int j = 0; j < 8; ++j) v[j] = (short)f2bf(p[j]);
    return v;
}

// r12: agent-scope (MALL) exchange, r8's EARLY-issue poll structure restored
// (measured fastest: early+vm1=1232us vs late+vm0=1596us — late issue exposes
// the full first RTT and drains the h-store ack in every vmcnt(0) wait).
__device__ __forceinline__ void issue4_dev(u32x4& v, const uint32_t* p) {
    asm volatile("global_load_dwordx4 %0, %1, off sc0 sc1"
                 : "+v"(v) : "v"(p) : "memory");
}
__device__ __forceinline__ void wait_vm1(u32x4& a, u32x4& b, u32x4& c, u32x4& d) {
    // vmcnt retires in issue order (m135): <=1 outstanding means the 4 older
    // poll loads are done while the younger fire-and-forget h-store may still
    // be in flight — we never pay for the store ack.
    asm volatile("s_waitcnt vmcnt(1)"
                 : "+v"(a), "+v"(b), "+v"(c), "+v"(d) :: "memory");
}
__device__ __forceinline__ void wait_vm0(u32x4& a, u32x4& b, u32x4& c, u32x4& d) {
    asm volatile("s_waitcnt vmcnt(0)"
                 : "+v"(a), "+v"(b), "+v"(c), "+v"(d) :: "memory");
}
__device__ __forceinline__ uint32_t has_sent(const u32x4& v) {
    return (uint32_t)(v[0] == SENT) | (uint32_t)(v[1] == SENT) |
           (uint32_t)(v[2] == SENT) | (uint32_t)(v[3] == SENT);
}

// Fill hbuf with the sentinel before the recurrence.
__global__ __launch_bounds__(256) void lstm_init(uint32_t* __restrict__ hbuf)
{
    const size_t n4 = (size_t)(T_STEPS + 1) * BATCH * HDIM / 2 / 4;
    u32x4 s; s[0] = SENT; s[1] = SENT; s[2] = SENT; s[3] = SENT;
    u32x4* p = (u32x4*)hbuf;
    for (size_t i = (size_t)blockIdx.x * 256 + threadIdx.x; i < n4;
         i += (size_t)gridDim.x * 256)
        p[i] = s;
}

// Persistent recurrence kernel. 256 blocks = 16 groups x 16 members.
// Group owns 16 batch rows; member owns 32 H columns (x4 gates, one per wave).
// Weights live in registers as MFMA B-fragments for the whole kernel.
// r12 = r8's exchange structure (early poll issue at barrier, store_x,
// pointwise, h-store YOUNGEST, wait vmcnt(1), conditional-reissue rounds)
// + two r11-proven grafts:
//  - bias+activation on the producer waves pre-barrier (post-barrier path
//    shrinks -> peers' h-stores land earlier -> round-2 hit rate up);
//  - own 32 columns written straight to hA LDS; own chunk-cols skip polling.
__global__ __launch_bounds__(256, 1) void lstm_rec(
    const float* __restrict__ x,
    const float* __restrict__ Wxi, const float* __restrict__ Wxf,
    const float* __restrict__ Wxo, const float* __restrict__ Wxc,
    const float* __restrict__ Whi, const float* __restrict__ bhi,
    const float* __restrict__ Whf, const float* __restrict__ bhf,
    const float* __restrict__ Who, const float* __restrict__ bho,
    const float* __restrict__ Whc, const float* __restrict__ bhc,
    uint16_t* __restrict__ hbuf)      // [T_STEPS+1][BATCH][HDIM] bf16 (scratch)
{
    __shared__ __align__(16) uint8_t hA[16 * LDA];   // 16.6 KB
    __shared__ __align__(16) uint8_t xA[16 * LDX];   // 3.3 KB
    __shared__ float gbuf[4 * 16 * 33];              // 8.4 KB

    const int tid  = threadIdx.x;
    const int bid  = blockIdx.x;
    const int xcd  = bid & 7;
    const int slot = bid >> 3;
    const int grp  = xcd * 2 + (slot >> 4);
    const int mem  = slot & 15;
    const int b0   = grp * BBLK;
    const int hs   = mem * HS;

    const int wave  = tid >> 6;       // gate: 0=i 1=f 2=o 3=c
    const int lane  = tid & 63;
    const int col16 = lane & 15;
    const int quad  = lane >> 4;

    const float* Wh  = (wave == 0) ? Whi : (wave == 1) ? Whf : (wave == 2) ? Who : Whc;
    const float* Wxp = (wave == 0) ? Wxi : (wave == 1) ? Wxf : (wave == 2) ? Wxo : Wxc;
    const float* bg  = (wave == 0) ? bhi : (wave == 1) ? bhf : (wave == 2) ? bho : bhc;

    // ---- B-fragments (weights) into registers, once (fp32 -> bf16 RNE) ----
    s8v bh[2][16];
#pragma unroll
    for (int nt = 0; nt < 2; ++nt) {
        const float* rowp = Wh + (size_t)(hs + nt * 16 + col16) * HDIM;
#pragma unroll
        for (int kt = 0; kt < 16; ++kt)
            bh[nt][kt] = cvt8(rowp + kt * 32 + quad * 8);
    }
    s8v bx[2][3];
#pragma unroll
    for (int nt = 0; nt < 2; ++nt) {
        const float* rowp = Wxp + (size_t)(hs + nt * 16 + col16) * DIN;
#pragma unroll
        for (int kt = 0; kt < 3; ++kt) {
            s8v v;
#pragma unroll
            for (int j = 0; j < 8; ++j) {
                int k = kt * 32 + quad * 8 + j;
                v[j] = (k < DIN) ? (short)f2bf(rowp[k]) : (short)0;
            }
            bx[nt][kt] = v;
        }
    }
    // per-wave gate bias for the producer-side activation
    const float bg0 = bg[hs + col16];
    const float bg1 = bg[hs + 16 + col16];

    // ---- pointwise mapping: thread -> (row r, cols c0,c0+1) of 16x32 slice ----
    const int r  = tid >> 4;
    const int c0 = (tid & 15) * 2;
    float C0 = 0.f, C1 = 0.f;

    uint32_t* hbuf32 = (uint32_t*)hbuf;
    const size_t hslot = ((size_t)(b0 + r) * HDIM + hs + c0) >> 1;

    // ---- refill chunk mapping: chunk c = tid + 256q -> row c>>6, 16B col c&63
    const int rrow[4] = { tid >> 6, (tid + 256) >> 6, (tid + 512) >> 6, (tid + 768) >> 6 };
    const int rc8     = tid & 63;
    // own 32 columns = 4 chunk-cols; they arrive via LDS, never via poll
    const uint32_t ownm = (rc8 >= mem * 4 && rc8 < mem * 4 + 4) ? 1u : 0u;

    // ---- x prefetch (fp32 registers) ----
    float xreg[6];
    auto load_x = [&](int t) {
#pragma unroll
        for (int j = 0; j < 6; ++j) {
            int v = tid + j * 256;
            int row = v / 96, k = v % 96;
            xreg[j] = (k < DIN) ? x[(size_t)(t * BATCH + b0 + row) * DIN + k] : 0.f;
        }
    };
    auto store_x = [&]() {
#pragma unroll
        for (int j = 0; j < 6; ++j) {
            int v = tid + j * 256;
            int row = v / 96, k = v % 96;
            *(uint16_t*)(xA + row * LDX + k * 2) = f2bf(xreg[j]);
        }
    };

    // init: h(0)=0 in LDS, stage x(0)
    load_x(0);
    for (int j = tid; j < 16 * LDA / 16; j += 256) {
        s8v z;
#pragma unroll
        for (int q = 0; q < 8; ++q) z[q] = 0;
        ((s8v*)hA)[j] = z;
    }
    store_x();
    __syncthreads();

    u32x4 v0 = {SENT, SENT, SENT, SENT};
    u32x4 v1 = v0, v2 = v0, v3 = v0;

    for (int t = 0; t < T_STEPS; ++t) {
        const int last = (t == T_STEPS - 1);

        // x(t+1) loads fly under the GEMM (arrived by store_x time)
        if (!last) load_x(t + 1);

        // ---- GEMM: pre-activations for this wave's gate, 16 rows x 32 cols ----
        f4v acc0 = {0.f, 0.f, 0.f, 0.f}, acc1 = {0.f, 0.f, 0.f, 0.f};
#pragma unroll
        for (int kt = 0; kt < 16; ++kt) {
            s8v a = *(const s8v*)(hA + col16 * LDA + kt * 64 + quad * 16);
            acc0 = __builtin_amdgcn_mfma_f32_16x16x32_bf16(a, bh[0][kt], acc0, 0, 0, 0);
            acc1 = __builtin_amdgcn_mfma_f32_16x16x32_bf16(a, bh[1][kt], acc1, 0, 0, 0);
        }
#pragma unroll
        for (int kt = 0; kt < 3; ++kt) {
            s8v a = *(const s8v*)(xA + col16 * LDX + kt * 64 + quad * 16);
            acc0 = __builtin_amdgcn_mfma_f32_16x16x32_bf16(a, bx[0][kt], acc0, 0, 0, 0);
            acc1 = __builtin_amdgcn_mfma_f32_16x16x32_bf16(a, bx[1][kt], acc1, 0, 0, 0);
        }
        // bias + activation on the producer wave (parallel across 4 waves,
        // off the post-barrier serial path). C/D layout: col=lane&15, row=quad*4+rr.
        // Same math/order as consumer-side would do -> bit-identical (r11-proven).
#pragma unroll
        for (int rr = 0; rr < 4; ++rr) {
            float a0 = acc0[rr] + bg0;
            float a1 = acc1[rr] + bg1;
            if (wave == 3) { a0 = tanh_f(a0); a1 = tanh_f(a1); }
            else           { a0 = sigm(a0);   a1 = sigm(a1);   }
            int b = quad * 4 + rr;
            gbuf[(wave * 16 + b) * 33 + col16]      = a0;
            gbuf[(wave * 16 + b) * 33 + 16 + col16] = a1;
        }

        __syncthreads();

        // ---- EARLY poll issue (r8): round-1 RTT hides under store_x +
        // pointwise + h-store; loads stay OLDER than the h-store so
        // wait_vm1 never pays the store ack.
        const uint32_t* src = hbuf32 + (size_t)(t + 1) * (BATCH * HDIM / 2)
                                     + (size_t)b0 * (HDIM / 2);
        const uint32_t* p0 = src + (size_t)rrow[0] * (HDIM / 2) + rc8 * 4;
        const uint32_t* p1 = src + (size_t)rrow[1] * (HDIM / 2) + rc8 * 4;
        const uint32_t* p2 = src + (size_t)rrow[2] * (HDIM / 2) + rc8 * 4;
        const uint32_t* p3 = src + (size_t)rrow[3] * (HDIM / 2) + rc8 * 4;

        if (!last) {
            if (!ownm) {
                issue4_dev(v0, p0); issue4_dev(v1, p1);
                issue4_dev(v2, p2); issue4_dev(v3, p3);
            }
            store_x();   // xA free after barrier; x regs arrived during GEMM
        }

        // ---- pointwise (gates pre-activated): 2 FMA + tanh(C) + pack ----
        float I0 = gbuf[(0 * 16 + r) * 33 + c0], I1 = gbuf[(0 * 16 + r) * 33 + c0 + 1];
        float F0 = gbuf[(1 * 16 + r) * 33 + c0], F1 = gbuf[(1 * 16 + r) * 33 + c0 + 1];
        float O0 = gbuf[(2 * 16 + r) * 33 + c0], O1 = gbuf[(2 * 16 + r) * 33 + c0 + 1];
        float G0 = gbuf[(3 * 16 + r) * 33 + c0], G1 = gbuf[(3 * 16 + r) * 33 + c0 + 1];
        C0 = F0 * C0 + I0 * G0;
        C1 = F1 * C1 + I1 * G1;
        float h0 = O0 * tanh_f(C0);
        float h1 = O1 * tanh_f(C1);

        // fire-and-forget agent store (coherence point); no fence, no drain;
        // YOUNGEST vmem op -> excluded from wait_vm1
        uint32_t packed = (uint32_t)f2bf(h0) | ((uint32_t)f2bf(h1) << 16);
        __hip_atomic_store(&hbuf32[(size_t)(t + 1) * (BATCH * HDIM / 2) + hslot],
                           packed, __ATOMIC_RELAXED, __HIP_MEMORY_SCOPE_AGENT);

        if (last) break;

        // own columns go straight to LDS — no exchange round-trip for them
        *(uint32_t*)(hA + r * LDA + (hs + c0) * 2) = packed;

        // ---- poll rounds: batched reissue of pending chunks, one RTT/round ----
        wait_vm1(v0, v1, v2, v3);   // 4 poll loads done; h-store stays in flight
        uint32_t s0 = ownm ? 0u : has_sent(v0);
        uint32_t s1 = ownm ? 0u : has_sent(v1);
        uint32_t s2 = ownm ? 0u : has_sent(v2);
        uint32_t s3 = ownm ? 0u : has_sent(v3);
        int round = 0;
        while (s0 | s1 | s2 | s3) {
            if (++round > 50000) break;   // never hang
            if (round >= 6) __builtin_amdgcn_s_sleep(2);
            if (s0) issue4_dev(v0, p0);
            if (s1) issue4_dev(v1, p1);
            if (s2) issue4_dev(v2, p2);
            if (s3) issue4_dev(v3, p3);
            wait_vm0(v0, v1, v2, v3);
            s0 = has_sent(v0); s1 = has_sent(v1);
            s2 = has_sent(v2); s3 = has_sent(v3);
        }
        if (!ownm) {
            *(u32x4*)(hA + rrow[0] * LDA + rc8 * 16) = v0;
            *(u32x4*)(hA + rrow[1] * LDA + rc8 * 16) = v1;
            *(u32x4*)(hA + rrow[2] * LDA + rc8 * 16) = v2;
            *(u32x4*)(hA + rrow[3] * LDA + rc8 * 16) = v3;
        }

        __syncthreads();
    }
}

// Readout: out[t,b,:] = h[t+1] @ Wro^T + bro.  MFMA, N padded 33->48. fp32 out.
__global__ __launch_bounds__(256, 1) void lstm_out(
    const uint16_t* __restrict__ hbuf,
    const float* __restrict__ Wro, const float* __restrict__ bro,
    float* __restrict__ out)
{
    __shared__ __align__(16) uint8_t hT[64 * LDA];   // 66.6 KB

    const int tid   = threadIdx.x;
    const int bid   = blockIdx.x;
    const int wave  = tid >> 6;
    const int lane  = tid & 63;
    const int col16 = lane & 15;
    const int quad  = lane >> 4;

    s8v bw[3][16];
    float bias[3];
#pragma unroll
    for (int nt = 0; nt < 3; ++nt) {
        int o = nt * 16 + col16;
        bias[nt] = (o < NOUT) ? bro[o] : 0.f;
#pragma unroll
        for (int kt = 0; kt < 16; ++kt) {
            if (o < NOUT) {
                bw[nt][kt] = cvt8(Wro + (size_t)o * HDIM + kt * 32 + quad * 8);
            } else {
                s8v z;
#pragma unroll
                for (int q = 0; q < 8; ++q) z[q] = 0;
                bw[nt][kt] = z;
            }
        }
    }

    const uint16_t* hsrc = hbuf + (size_t)BATCH * HDIM;  // skip t=0 slot

    for (int sub = 0; sub < 8; ++sub) {
        size_t row0 = (size_t)bid * 512 + (size_t)sub * 64;
#pragma unroll
        for (int j = 0; j < 16; ++j) {
            int v = tid + j * 256;
            int row = v >> 6, c8 = v & 63;
            s8v val = *(const s8v*)(hsrc + (row0 + row) * HDIM + c8 * 8);
            *(s8v*)(hT + row * LDA + c8 * 16) = val;
        }
        __syncthreads();

        f4v acc[3];
#pragma unroll
        for (int nt = 0; nt < 3; ++nt) acc[nt] = (f4v){0.f, 0.f, 0.f, 0.f};
#pragma unroll
        for (int kt = 0; kt < 16; ++kt) {
            s8v a = *(const s8v*)(hT + (wave * 16 + col16) * LDA + kt * 64 + quad * 16);
#pragma unroll
            for (int nt = 0; nt < 3; ++nt)
                acc[nt] = __builtin_amdgcn_mfma_f32_16x16x32_bf16(a, bw[nt][kt], acc[nt], 0, 0, 0);
        }
#pragma unroll
        for (int nt = 0; nt < 3; ++nt) {
            int o = nt * 16 + col16;
            if (o < NOUT) {
#pragma unroll
                for (int rr = 0; rr < 4; ++rr) {
                    size_t rg = row0 + (size_t)wave * 16 + quad * 4 + rr;
                    out[rg * NOUT + o] = acc[nt][rr] + bias[nt];
                }
            }
        }
        __syncthreads();
    }
}

extern "C" void kernel_launch(void* const* d_in, const int* in_sizes, int n_in,
                              void* d_out, int out_size, void* d_ws, size_t ws_size,
                              hipStream_t stream)
{
    const float* x   = (const float*)d_in[0];
    const float* Wxi = (const float*)d_in[1];
    const float* Wxf = (const float*)d_in[2];
    const float* Wxo = (const float*)d_in[3];
    const float* Wxc = (const float*)d_in[4];
    const float* Whi = (const float*)d_in[5];
    const float* bhi = (const float*)d_in[6];
    const float* Whf = (const float*)d_in[7];
    const float* bhf = (const float*)d_in[8];
    const float* Who = (const float*)d_in[9];
    const float* bho = (const float*)d_in[10];
    const float* Whc = (const float*)d_in[11];
    const float* bhc = (const float*)d_in[12];
    const float* Wro = (const float*)d_in[13];
    const float* bro = (const float*)d_in[14];
    float* out = (float*)d_out;

    uint16_t* hbuf = (uint16_t*)d_ws;   // (T+1)*B*H*2 = 134.5 MB

    lstm_init<<<2048, 256, 0, stream>>>((uint32_t*)hbuf);
    lstm_rec<<<256, 256, 0, stream>>>(x, Wxi, Wxf, Wxo, Wxc,
                                      Whi, bhi, Whf, bhf, Who, bho, Whc, bhc,
                                      hbuf);
    lstm_out<<<256, 256, 0, stream>>>(hbuf, Wro, bro, out);
}

// Round 7
// 1250.071 us; speedup vs baseline: 1.3629x; 1.1773x over previous
//
#include <hip/hip_runtime.h>
#include <hip/hip_bf16.h>
#include <stdint.h>

#define T_STEPS 512
#define BATCH   256
#define DIN     85
#define HDIM    512
#define NOUT    33

#define BBLK  16     // batch rows per group
#define HS    32     // H columns per block
#define LDA   1040   // bytes per padded row of h A-tile (520 elems, 16B-aligned)
#define LDX   208    // bytes per padded row of x A-tile (104 elems)

// bf16 NaN|NaN pair — unreachable as packed h output (|h|<1, finite),
// used as the "not yet written" sentinel so the data is its own flag.
#define SENT  0x7FC07FC0u

typedef __attribute__((ext_vector_type(8))) short s8v;       // 8 x bf16
typedef __attribute__((ext_vector_type(4))) float f4v;       // MFMA accumulator
typedef __attribute__((ext_vector_type(4))) uint32_t u32x4;  // 16B chunk

__device__ __forceinline__ uint16_t f2bf(float f) {
    uint32_t x = __builtin_bit_cast(uint32_t, f);
    uint32_t r = (x + 0x7fffu + ((x >> 16) & 1u)) >> 16;
    return (uint16_t)r;
}
__device__ __forceinline__ float sigm(float v) {
    v = fminf(fmaxf(v, -30.f), 30.f);
    return 1.f / (1.f + __expf(-v));
}
__device__ __forceinline__ float tanh_f(float v) {
    v = fminf(fmaxf(v, -15.f), 15.f);
    float e = __expf(2.f * v);
    return (e - 1.f) / (e + 1.f);
}
__device__ __forceinline__ s8v cvt8(const float* p) {
    s8v v;
#pragma unroll
    for (int j = 0; j < 8; ++j) v[j] = (short)f2bf(p[j]);
    return v;
}

// r13: r8's proven exchange structure (early poll issue, h-store youngest,
// wait vmcnt(1)); the ONLY reorder vs r8 is store_x moved after the h-store.
// Model (validated by r11/r12 failures): work after the poll-issue is free
// (overlaps RTT); work before the barrier is always paid. store_x after the
// h-store (a) issues the store ~100cy earlier for peers' round-2 sample and
// (b) adds ~100cy of RTT hiding before wait_vm1. Producer-side activation
// (r12) reverted — it moved overlap-free work into the paid region.
__device__ __forceinline__ void issue4_dev(u32x4& v, const uint32_t* p) {
    asm volatile("global_load_dwordx4 %0, %1, off sc0 sc1"
                 : "+v"(v) : "v"(p) : "memory");
}
__device__ __forceinline__ void wait_vm1(u32x4& a, u32x4& b, u32x4& c, u32x4& d) {
    // vmcnt retires oldest-first (m135): <=1 outstanding means the 4 older
    // poll loads are done while the younger fire-and-forget h-store may still
    // be in flight — we never pay for the store ack.
    asm volatile("s_waitcnt vmcnt(1)"
                 : "+v"(a), "+v"(b), "+v"(c), "+v"(d) :: "memory");
}
__device__ __forceinline__ void wait_vm0(u32x4& a, u32x4& b, u32x4& c, u32x4& d) {
    asm volatile("s_waitcnt vmcnt(0)"
                 : "+v"(a), "+v"(b), "+v"(c), "+v"(d) :: "memory");
}
__device__ __forceinline__ uint32_t has_sent(const u32x4& v) {
    return (uint32_t)(v[0] == SENT) | (uint32_t)(v[1] == SENT) |
           (uint32_t)(v[2] == SENT) | (uint32_t)(v[3] == SENT);
}

// Fill hbuf with the sentinel before the recurrence.
__global__ __launch_bounds__(256) void lstm_init(uint32_t* __restrict__ hbuf)
{
    const size_t n4 = (size_t)(T_STEPS + 1) * BATCH * HDIM / 2 / 4;
    u32x4 s; s[0] = SENT; s[1] = SENT; s[2] = SENT; s[3] = SENT;
    u32x4* p = (u32x4*)hbuf;
    for (size_t i = (size_t)blockIdx.x * 256 + threadIdx.x; i < n4;
         i += (size_t)gridDim.x * 256)
        p[i] = s;
}

// Persistent recurrence kernel. 256 blocks = 16 groups x 16 members.
// Group owns 16 batch rows; member owns 32 H columns (x4 gates, one per wave).
// Weights live in registers as MFMA B-fragments for the whole kernel.
// Post-barrier order (r13): poll-issue -> pointwise -> h-store -> own-col LDS
// -> store_x -> wait_vm1 -> conditional-reissue rounds -> hA writes -> barrier.
__global__ __launch_bounds__(256, 1) void lstm_rec(
    const float* __restrict__ x,
    const float* __restrict__ Wxi, const float* __restrict__ Wxf,
    const float* __restrict__ Wxo, const float* __restrict__ Wxc,
    const float* __restrict__ Whi, const float* __restrict__ bhi,
    const float* __restrict__ Whf, const float* __restrict__ bhf,
    const float* __restrict__ Who, const float* __restrict__ bho,
    const float* __restrict__ Whc, const float* __restrict__ bhc,
    uint16_t* __restrict__ hbuf)      // [T_STEPS+1][BATCH][HDIM] bf16 (scratch)
{
    __shared__ __align__(16) uint8_t hA[16 * LDA];   // 16.6 KB
    __shared__ __align__(16) uint8_t xA[16 * LDX];   // 3.3 KB
    __shared__ float gbuf[4 * 16 * 33];              // 8.4 KB

    const int tid  = threadIdx.x;
    const int bid  = blockIdx.x;
    const int xcd  = bid & 7;
    const int slot = bid >> 3;
    const int grp  = xcd * 2 + (slot >> 4);
    const int mem  = slot & 15;
    const int b0   = grp * BBLK;
    const int hs   = mem * HS;

    const int wave  = tid >> 6;       // gate: 0=i 1=f 2=o 3=c
    const int lane  = tid & 63;
    const int col16 = lane & 15;
    const int quad  = lane >> 4;

    const float* Wh  = (wave == 0) ? Whi : (wave == 1) ? Whf : (wave == 2) ? Who : Whc;
    const float* Wxp = (wave == 0) ? Wxi : (wave == 1) ? Wxf : (wave == 2) ? Wxo : Wxc;

    // ---- B-fragments (weights) into registers, once (fp32 -> bf16 RNE) ----
    s8v bh[2][16];
#pragma unroll
    for (int nt = 0; nt < 2; ++nt) {
        const float* rowp = Wh + (size_t)(hs + nt * 16 + col16) * HDIM;
#pragma unroll
        for (int kt = 0; kt < 16; ++kt)
            bh[nt][kt] = cvt8(rowp + kt * 32 + quad * 8);
    }
    s8v bx[2][3];
#pragma unroll
    for (int nt = 0; nt < 2; ++nt) {
        const float* rowp = Wxp + (size_t)(hs + nt * 16 + col16) * DIN;
#pragma unroll
        for (int kt = 0; kt < 3; ++kt) {
            s8v v;
#pragma unroll
            for (int j = 0; j < 8; ++j) {
                int k = kt * 32 + quad * 8 + j;
                v[j] = (k < DIN) ? (short)f2bf(rowp[k]) : (short)0;
            }
            bx[nt][kt] = v;
        }
    }

    // ---- pointwise mapping: thread -> (row r, cols c0,c0+1) of 16x32 slice ----
    const int r  = tid >> 4;
    const int c0 = (tid & 15) * 2;
    const float bi0 = bhi[hs + c0], bi1 = bhi[hs + c0 + 1];
    const float bf0 = bhf[hs + c0], bf1 = bhf[hs + c0 + 1];
    const float bo0 = bho[hs + c0], bo1 = bho[hs + c0 + 1];
    const float bc0 = bhc[hs + c0], bc1 = bhc[hs + c0 + 1];
    float C0 = 0.f, C1 = 0.f;

    uint32_t* hbuf32 = (uint32_t*)hbuf;
    const size_t hslot = ((size_t)(b0 + r) * HDIM + hs + c0) >> 1;

    // ---- refill chunk mapping: chunk c = tid + 256q -> row c>>6, 16B col c&63
    const int rrow[4] = { tid >> 6, (tid + 256) >> 6, (tid + 512) >> 6, (tid + 768) >> 6 };
    const int rc8     = tid & 63;
    // own 32 columns = 4 chunk-cols; they arrive via LDS, never via poll
    const uint32_t ownm = (rc8 >= mem * 4 && rc8 < mem * 4 + 4) ? 1u : 0u;

    // ---- x prefetch (fp32 registers) ----
    float xreg[6];
    auto load_x = [&](int t) {
#pragma unroll
        for (int j = 0; j < 6; ++j) {
            int v = tid + j * 256;
            int row = v / 96, k = v % 96;
            xreg[j] = (k < DIN) ? x[(size_t)(t * BATCH + b0 + row) * DIN + k] : 0.f;
        }
    };
    auto store_x = [&]() {
#pragma unroll
        for (int j = 0; j < 6; ++j) {
            int v = tid + j * 256;
            int row = v / 96, k = v % 96;
            *(uint16_t*)(xA + row * LDX + k * 2) = f2bf(xreg[j]);
        }
    };

    // init: h(0)=0 in LDS, stage x(0)
    load_x(0);
    for (int j = tid; j < 16 * LDA / 16; j += 256) {
        s8v z;
#pragma unroll
        for (int q = 0; q < 8; ++q) z[q] = 0;
        ((s8v*)hA)[j] = z;
    }
    store_x();
    __syncthreads();

    u32x4 v0 = {SENT, SENT, SENT, SENT};
    u32x4 v1 = v0, v2 = v0, v3 = v0;

    for (int t = 0; t < T_STEPS; ++t) {
        const int last = (t == T_STEPS - 1);

        // x(t+1) loads fly under the GEMM (done well before store_x needs them)
        if (!last) load_x(t + 1);

        // ---- GEMM: pre-activations for this wave's gate, 16 rows x 32 cols ----
        f4v acc0 = {0.f, 0.f, 0.f, 0.f}, acc1 = {0.f, 0.f, 0.f, 0.f};
#pragma unroll
        for (int kt = 0; kt < 16; ++kt) {
            s8v a = *(const s8v*)(hA + col16 * LDA + kt * 64 + quad * 16);
            acc0 = __builtin_amdgcn_mfma_f32_16x16x32_bf16(a, bh[0][kt], acc0, 0, 0, 0);
            acc1 = __builtin_amdgcn_mfma_f32_16x16x32_bf16(a, bh[1][kt], acc1, 0, 0, 0);
        }
#pragma unroll
        for (int kt = 0; kt < 3; ++kt) {
            s8v a = *(const s8v*)(xA + col16 * LDX + kt * 64 + quad * 16);
            acc0 = __builtin_amdgcn_mfma_f32_16x16x32_bf16(a, bx[0][kt], acc0, 0, 0, 0);
            acc1 = __builtin_amdgcn_mfma_f32_16x16x32_bf16(a, bx[1][kt], acc1, 0, 0, 0);
        }
        // Raw pre-activations to LDS (r8 style — NO producer-side activation,
        // keep the barrier as early as possible). C/D: col=lane&15, row=quad*4+rr
#pragma unroll
        for (int rr = 0; rr < 4; ++rr) {
            int b = quad * 4 + rr;
            gbuf[(wave * 16 + b) * 33 + col16]      = acc0[rr];
            gbuf[(wave * 16 + b) * 33 + 16 + col16] = acc1[rr];
        }

        __syncthreads();

        // ---- EARLY poll issue: round-1 RTT hides under pointwise + h-store
        // + store_x; polls stay OLDER than the h-store so wait_vm1 never pays
        // the store ack.
        const uint32_t* src = hbuf32 + (size_t)(t + 1) * (BATCH * HDIM / 2)
                                     + (size_t)b0 * (HDIM / 2);
        const uint32_t* p0 = src + (size_t)rrow[0] * (HDIM / 2) + rc8 * 4;
        const uint32_t* p1 = src + (size_t)rrow[1] * (HDIM / 2) + rc8 * 4;
        const uint32_t* p2 = src + (size_t)rrow[2] * (HDIM / 2) + rc8 * 4;
        const uint32_t* p3 = src + (size_t)rrow[3] * (HDIM / 2) + rc8 * 4;

        if (!last && !ownm) {
            issue4_dev(v0, p0); issue4_dev(v1, p1);
            issue4_dev(v2, p2); issue4_dev(v3, p3);
        }

        // ---- pointwise (full, consumer-side — overlaps poll RTT) ----
        float pi0 = gbuf[(0 * 16 + r) * 33 + c0] + bi0;
        float pi1 = gbuf[(0 * 16 + r) * 33 + c0 + 1] + bi1;
        float pf0 = gbuf[(1 * 16 + r) * 33 + c0] + bf0;
        float pf1 = gbuf[(1 * 16 + r) * 33 + c0 + 1] + bf1;
        float po0 = gbuf[(2 * 16 + r) * 33 + c0] + bo0;
        float po1 = gbuf[(2 * 16 + r) * 33 + c0 + 1] + bo1;
        float pc0 = gbuf[(3 * 16 + r) * 33 + c0] + bc0;
        float pc1 = gbuf[(3 * 16 + r) * 33 + c0 + 1] + bc1;

        float I0 = sigm(pi0), F0 = sigm(pf0), O0 = sigm(po0), G0 = tanh_f(pc0);
        float I1 = sigm(pi1), F1 = sigm(pf1), O1 = sigm(po1), G1 = tanh_f(pc1);
        C0 = F0 * C0 + I0 * G0;
        C1 = F1 * C1 + I1 * G1;
        float h0 = O0 * tanh_f(C0);
        float h1 = O1 * tanh_f(C1);

        // fire-and-forget agent store (coherence point); no fence, no drain;
        // YOUNGEST vmem op -> excluded from wait_vm1
        uint32_t packed = (uint32_t)f2bf(h0) | ((uint32_t)f2bf(h1) << 16);
        __hip_atomic_store(&hbuf32[(size_t)(t + 1) * (BATCH * HDIM / 2) + hslot],
                           packed, __ATOMIC_RELAXED, __HIP_MEMORY_SCOPE_AGENT);

        if (last) break;

        // own columns go straight to LDS — no exchange round-trip for them
        *(uint32_t*)(hA + r * LDA + (hs + c0) * 2) = packed;

        // store_x AFTER the h-store (r13 reorder): the ~100cy of f2bf+LDS
        // writes now hide poll RTT instead of delaying the h-store. The
        // compiler's waitcnt here covers only the OLDER x-loads.
        store_x();

        // ---- poll rounds: batched reissue of pending chunks, one RTT/round ----
        wait_vm1(v0, v1, v2, v3);   // 4 poll loads done; h-store stays in flight
        uint32_t s0 = ownm ? 0u : has_sent(v0);
        uint32_t s1 = ownm ? 0u : has_sent(v1);
        uint32_t s2 = ownm ? 0u : has_sent(v2);
        uint32_t s3 = ownm ? 0u : has_sent(v3);
        int round = 0;
        while (s0 | s1 | s2 | s3) {
            if (++round > 50000) break;   // never hang
            if (round >= 6) __builtin_amdgcn_s_sleep(2);
            if (s0) issue4_dev(v0, p0);
            if (s1) issue4_dev(v1, p1);
            if (s2) issue4_dev(v2, p2);
            if (s3) issue4_dev(v3, p3);
            wait_vm0(v0, v1, v2, v3);
            s0 = has_sent(v0); s1 = has_sent(v1);
            s2 = has_sent(v2); s3 = has_sent(v3);
        }
        if (!ownm) {
            *(u32x4*)(hA + rrow[0] * LDA + rc8 * 16) = v0;
            *(u32x4*)(hA + rrow[1] * LDA + rc8 * 16) = v1;
            *(u32x4*)(hA + rrow[2] * LDA + rc8 * 16) = v2;
            *(u32x4*)(hA + rrow[3] * LDA + rc8 * 16) = v3;
        }

        __syncthreads();
    }
}

// Readout: out[t,b,:] = h[t+1] @ Wro^T + bro.  MFMA, N padded 33->48. fp32 out.
__global__ __launch_bounds__(256, 1) void lstm_out(
    const uint16_t* __restrict__ hbuf,
    const float* __restrict__ Wro, const float* __restrict__ bro,
    float* __restrict__ out)
{
    __shared__ __align__(16) uint8_t hT[64 * LDA];   // 66.6 KB

    const int tid   = threadIdx.x;
    const int bid   = blockIdx.x;
    const int wave  = tid >> 6;
    const int lane  = tid & 63;
    const int col16 = lane & 15;
    const int quad  = lane >> 4;

    s8v bw[3][16];
    float bias[3];
#pragma unroll
    for (int nt = 0; nt < 3; ++nt) {
        int o = nt * 16 + col16;
        bias[nt] = (o < NOUT) ? bro[o] : 0.f;
#pragma unroll
        for (int kt = 0; kt < 16; ++kt) {
            if (o < NOUT) {
                bw[nt][kt] = cvt8(Wro + (size_t)o * HDIM + kt * 32 + quad * 8);
            } else {
                s8v z;
#pragma unroll
                for (int q = 0; q < 8; ++q) z[q] = 0;
                bw[nt][kt] = z;
            }
        }
    }

    const uint16_t* hsrc = hbuf + (size_t)BATCH * HDIM;  // skip t=0 slot

    for (int sub = 0; sub < 8; ++sub) {
        size_t row0 = (size_t)bid * 512 + (size_t)sub * 64;
#pragma unroll
        for (int j = 0; j < 16; ++j) {
            int v = tid + j * 256;
            int row = v >> 6, c8 = v & 63;
            s8v val = *(const s8v*)(hsrc + (row0 + row) * HDIM + c8 * 8);
            *(s8v*)(hT + row * LDA + c8 * 16) = val;
        }
        __syncthreads();

        f4v acc[3];
#pragma unroll
        for (int nt = 0; nt < 3; ++nt) acc[nt] = (f4v){0.f, 0.f, 0.f, 0.f};
#pragma unroll
        for (int kt = 0; kt < 16; ++kt) {
            s8v a = *(const s8v*)(hT + (wave * 16 + col16) * LDA + kt * 64 + quad * 16);
#pragma unroll
            for (int nt = 0; nt < 3; ++nt)
                acc[nt] = __builtin_amdgcn_mfma_f32_16x16x32_bf16(a, bw[nt][kt], acc[nt], 0, 0, 0);
        }
#pragma unroll
        for (int nt = 0; nt < 3; ++nt) {
            int o = nt * 16 + col16;
            if (o < NOUT) {
#pragma unroll
                for (int rr = 0; rr < 4; ++rr) {
                    size_t rg = row0 + (size_t)wave * 16 + quad * 4 + rr;
                    out[rg * NOUT + o] = acc[nt][rr] + bias[nt];
                }
            }
        }
        __syncthreads();
    }
}

extern "C" void kernel_launch(void* const* d_in, const int* in_sizes, int n_in,
                              void* d_out, int out_size, void* d_ws, size_t ws_size,
                              hipStream_t stream)
{
    const float* x   = (const float*)d_in[0];
    const float* Wxi = (const float*)d_in[1];
    const float* Wxf = (const float*)d_in[2];
    const float* Wxo = (const float*)d_in[3];
    const float* Wxc = (const float*)d_in[4];
    const float* Whi = (const float*)d_in[5];
    const float* bhi = (const float*)d_in[6];
    const float* Whf = (const float*)d_in[7];
    const float* bhf = (const float*)d_in[8];
    const float* Who = (const float*)d_in[9];
    const float* bho = (const float*)d_in[10];
    const float* Whc = (const float*)d_in[11];
    const float* bhc = (const float*)d_in[12];
    const float* Wro = (const float*)d_in[13];
    const float* bro = (const float*)d_in[14];
    float* out = (float*)d_out;

    uint16_t* hbuf = (uint16_t*)d_ws;   // (T+1)*B*H*2 = 134.5 MB

    lstm_init<<<2048, 256, 0, stream>>>((uint32_t*)hbuf);
    lstm_rec<<<256, 256, 0, stream>>>(x, Wxi, Wxf, Wxo, Wxc,
                                      Whi, bhi, Whf, bhf, Who, bho, Whc, bhc,
                                      hbuf);
    lstm_out<<<256, 256, 0, stream>>>(hbuf, Wro, bro, out);
}